// Round 1
// baseline (1154.338 us; speedup 1.0000x reference)
//
#include <hip/hip_runtime.h>
#include <cstdint>

// ---------------------------------------------------------------------------
// CrossGraphMessagePassing, restructured:
//   PA[p] = h_prot @ att_w1[0:128]          PP[p] = h_prot @ proj_w1[0:128]
//   LA[l] = h_lig  @ att_w1[128:256] + b1a  LP[l] = h_lig  @ proj_w1[128:256] + b1p
//   per edge: pre = PA[p]+LA[l]+geo@Wg ; hidden=silu ; logit=hidden@w2+b2
//             w=exp(logit) (no max needed: |logit| small), g=exp(-d^2/32)
//             accumulate per-ligand: num += w*g*silu(preP), den += w, gws += w*g
//   per lig:  agg = (num/(den+1e-9)) @ proj_w2 + (gws/(den+1e-9))*proj_b2
//             out = LN(h_lig + agg)
// Edges counting-sorted by ligand so one block == one ligand (no float atomics).
// ---------------------------------------------------------------------------

__device__ __forceinline__ float siluf(float x) { return x / (1.0f + expf(-x)); }

__global__ void k_copy4(const float4* __restrict__ s, float4* __restrict__ d, int n) {
  int i = blockIdx.x * blockDim.x + threadIdx.x;
  int stride = gridDim.x * blockDim.x;
  for (; i < n; i += stride) d[i] = s[i];
}

// Tables: 8 rows/block, 256 threads (t<128 -> att table col d, t>=128 -> proj table col d).
// h tile staged transposed in LDS so the 8 broadcast reads per k are 2x ds_read_b128.
__global__ __launch_bounds__(256) void k_tables(
    const float* __restrict__ h, int nrows,
    const float* __restrict__ Wa, const float* __restrict__ Wp,   // 128x128 row-major (k,d)
    const float* __restrict__ ba, const float* __restrict__ bp,   // nullable
    float* __restrict__ TA, float* __restrict__ TP) {
  __shared__ float hT[128 * 8];  // [k][r]
  int t = threadIdx.x;
  int row0 = blockIdx.x * 8;
  for (int i = t; i < 1024; i += 256) {
    int r = i >> 7, k = i & 127;
    int gr = row0 + r;
    hT[k * 8 + r] = (gr < nrows) ? h[gr * 128 + k] : 0.0f;
  }
  __syncthreads();
  const float* W = (t < 128) ? Wa : Wp;
  const float* bias = (t < 128) ? ba : bp;
  float* T = (t < 128) ? TA : TP;
  int d = t & 127;
  float acc[8] = {0, 0, 0, 0, 0, 0, 0, 0};
  for (int k = 0; k < 128; ++k) {
    float w = W[k * 128 + d];
    const float4* h4 = reinterpret_cast<const float4*>(&hT[k * 8]);
    float4 a = h4[0], b = h4[1];
    acc[0] += a.x * w; acc[1] += a.y * w; acc[2] += a.z * w; acc[3] += a.w * w;
    acc[4] += b.x * w; acc[5] += b.y * w; acc[6] += b.z * w; acc[7] += b.w * w;
  }
  float bv = bias ? bias[d] : 0.0f;
  #pragma unroll
  for (int r = 0; r < 8; ++r) {
    int gr = row0 + r;
    if (gr < nrows) T[(size_t)gr * 128 + d] = acc[r] + bv;
  }
}

__global__ void k_hist(const int* __restrict__ l_idx, int ne, int* __restrict__ counts) {
  int i = blockIdx.x * blockDim.x + threadIdx.x;
  int stride = gridDim.x * blockDim.x;
  for (; i < ne; i += stride) atomicAdd(&counts[l_idx[i]], 1);
}

__global__ __launch_bounds__(1024) void k_scan(const int* __restrict__ counts,
                                               int* __restrict__ offsets, int n) {
  __shared__ int tsum[1024];
  int t = threadIdx.x;
  int per = (n + 1023) >> 10;
  int base = t * per;
  int s = 0;
  for (int i = 0; i < per; ++i) {
    int idx = base + i;
    if (idx < n) s += counts[idx];
  }
  tsum[t] = s;
  __syncthreads();
  for (int off = 1; off < 1024; off <<= 1) {
    int v = (t >= off) ? tsum[t - off] : 0;
    __syncthreads();
    tsum[t] += v;
    __syncthreads();
  }
  int run = (t == 0) ? 0 : tsum[t - 1];
  for (int i = 0; i < per; ++i) {
    int idx = base + i;
    if (idx < n) {
      offsets[idx] = run;
      run += counts[idx];
    }
  }
}

__global__ void k_scatter(const int* __restrict__ p_idx, const int* __restrict__ l_idx, int ne,
                          const int* __restrict__ offsets, int* __restrict__ cursor,
                          int* __restrict__ sorted_p) {
  int i = blockIdx.x * blockDim.x + threadIdx.x;
  int stride = gridDim.x * blockDim.x;
  for (; i < ne; i += stride) {
    int l = l_idx[i];
    int pos = offsets[l] + atomicAdd(&cursor[l], 1);
    sorted_p[pos] = p_idx[i];
  }
}

// One block (256 threads = 4 waves) per ligand. Lane owns dims d0=lane, d1=lane+64.
// Each wave processes every 4th edge of the segment independently (wave-uniform trip count).
__global__ __launch_bounds__(256) void k_edge(
    const float* __restrict__ PA, const float* __restrict__ PP,
    const float* __restrict__ LA, const float* __restrict__ LP,
    const float* __restrict__ prot_pos, const float* __restrict__ lig_pos,
    const int* __restrict__ offsets, const int* __restrict__ counts,
    const int* __restrict__ sorted_p,
    const float* __restrict__ att_w1, const float* __restrict__ att_w2,
    const float* __restrict__ att_b2,
    const float* __restrict__ proj_w1, const float* __restrict__ proj_w2,
    const float* __restrict__ proj_b2,
    const float* __restrict__ h_lig, const float* __restrict__ ln_g,
    const float* __restrict__ ln_b,
    float* __restrict__ out, int np_total) {
  int l = blockIdx.x;
  int t = threadIdx.x;
  int wave = t >> 6, lane = t & 63;
  int d0 = lane, d1 = lane + 64;

  // geo weights (rows 256..275 of att_w1/proj_w1) live in registers
  float Ga0[20], Ga1[20], Gp0[20], Gp1[20];
  #pragma unroll
  for (int k = 0; k < 20; ++k) {
    Ga0[k] = att_w1[(256 + k) * 128 + d0];
    Ga1[k] = att_w1[(256 + k) * 128 + d1];
    Gp0[k] = proj_w1[(256 + k) * 128 + d0];
    Gp1[k] = proj_w1[(256 + k) * 128 + d1];
  }
  float la0 = LA[(size_t)l * 128 + d0], la1 = LA[(size_t)l * 128 + d1];
  float lp0 = LP[(size_t)l * 128 + d0], lp1 = LP[(size_t)l * 128 + d1];
  float wa0 = att_w2[d0], wa1 = att_w2[d1];
  float lx = lig_pos[l * 3 + 0], ly = lig_pos[l * 3 + 1], lz = lig_pos[l * 3 + 2];
  float b2 = att_b2[0];

  int start = offsets[l];
  int cnt = counts[l];
  float acc0 = 0.0f, acc1 = 0.0f, den = 0.0f, gws = 0.0f;

  for (int i = wave; i < cnt; i += 4) {
    int p = sorted_p[start + i];
    float px = prot_pos[p * 3 + 0], py = prot_pos[p * 3 + 1], pz = prot_pos[p * 3 + 2];
    float dx = lx - px, dy = ly - py, dz = lz - pz;
    float d2r = dx * dx + dy * dy + dz * dz;
    float dist = sqrtf(d2r);
    float inv = 1.0f / (dist + 1e-8f);
    float geo[20];
    geo[0] = dist;
    geo[1] = dx * inv; geo[2] = dy * inv; geo[3] = dz * inv;
    #pragma unroll
    for (int j = 0; j < 16; ++j) {
      float c = (8.0f / 15.0f) * (float)j;  // linspace(0, 8, 16)
      float dd = dist - c;
      geo[4 + j] = expf(-2.0f * dd * dd);   // gamma = 1/(2*(8/16)^2) = 2
    }
    float pa0 = PA[(size_t)p * 128 + d0] + la0;
    float pa1 = PA[(size_t)p * 128 + d1] + la1;
    float pp0 = PP[(size_t)p * 128 + d0] + lp0;
    float pp1 = PP[(size_t)p * 128 + d1] + lp1;
    #pragma unroll
    for (int k = 0; k < 20; ++k) {
      pa0 += geo[k] * Ga0[k]; pa1 += geo[k] * Ga1[k];
      pp0 += geo[k] * Gp0[k]; pp1 += geo[k] * Gp1[k];
    }
    float h0 = siluf(pa0), h1 = siluf(pa1);
    float part = h0 * wa0 + h1 * wa1;
    #pragma unroll
    for (int off = 32; off; off >>= 1) part += __shfl_xor(part, off);
    float logit = part + b2;
    float w = expf(logit);                       // |logit| << 1: no max-shift needed
    float g = expf(-(dist * dist) * (1.0f / 32.0f));
    float s0 = siluf(pp0), s1 = siluf(pp1);
    float wg = w * g;
    acc0 += wg * s0; acc1 += wg * s1;
    den += w; gws += wg;
  }

  __shared__ float num[4][128];
  __shared__ float dsum[4], gsum[4];
  __shared__ float accv[128];
  __shared__ float xrow[128];
  __shared__ float part2[256];
  __shared__ float ssum[2], qsum[2];

  num[wave][d0] = acc0;
  num[wave][d1] = acc1;
  if (lane == 0) { dsum[wave] = den; gsum[wave] = gws; }
  __syncthreads();

  if (t < 128) {
    float dtot = dsum[0] + dsum[1] + dsum[2] + dsum[3];
    float invd = 1.0f / (dtot + 1e-9f);
    accv[t] = (num[0][t] + num[1][t] + num[2][t] + num[3][t]) * invd;
  }
  __syncthreads();

  // acc @ proj_w2: split k over the two thread-halves
  int d = t & 127;
  int k0 = (t < 128) ? 0 : 64;
  float sum = 0.0f;
  #pragma unroll 8
  for (int k = k0; k < k0 + 64; ++k) sum += accv[k] * proj_w2[k * 128 + d];
  part2[t] = sum;
  __syncthreads();

  if (t < 128) {
    float dtot = dsum[0] + dsum[1] + dsum[2] + dsum[3];
    float gtot = gsum[0] + gsum[1] + gsum[2] + gsum[3];
    float gval = gtot / (dtot + 1e-9f);
    float x = part2[t] + part2[t + 128] + gval * proj_b2[d] + h_lig[(size_t)l * 128 + d];
    xrow[d] = x;
    float s = x, q = x * x;
    #pragma unroll
    for (int off = 32; off; off >>= 1) {
      s += __shfl_xor(s, off);
      q += __shfl_xor(q, off);
    }
    if (lane == 0) { ssum[wave] = s; qsum[wave] = q; }
  }
  __syncthreads();
  if (t < 128) {
    float x = xrow[d];
    float mu = (ssum[0] + ssum[1]) * (1.0f / 128.0f);
    float var = (qsum[0] + qsum[1]) * (1.0f / 128.0f) - mu * mu;
    float y = (x - mu) * rsqrtf(var + 1e-5f) * ln_g[d] + ln_b[d];
    out[(size_t)(np_total + l) * 128 + d] = y;
  }
}

extern "C" void kernel_launch(void* const* d_in, const int* in_sizes, int n_in,
                              void* d_out, int out_size, void* d_ws, size_t ws_size,
                              hipStream_t stream) {
  const float* h_prot   = (const float*)d_in[0];
  const float* h_lig    = (const float*)d_in[1];
  const float* prot_pos = (const float*)d_in[2];
  const float* lig_pos  = (const float*)d_in[3];
  const int*   edges    = (const int*)d_in[4];
  const float* att_w1   = (const float*)d_in[5];
  const float* att_b1   = (const float*)d_in[6];
  const float* att_w2   = (const float*)d_in[7];
  const float* att_b2   = (const float*)d_in[8];
  const float* proj_w1  = (const float*)d_in[9];
  const float* proj_b1  = (const float*)d_in[10];
  const float* proj_w2  = (const float*)d_in[11];
  const float* proj_b2  = (const float*)d_in[12];
  const float* ln_g     = (const float*)d_in[13];
  const float* ln_b     = (const float*)d_in[14];

  int NP = in_sizes[0] / 128;
  int NL = in_sizes[1] / 128;
  int NE = in_sizes[4] / 2;
  const int* p_idx = edges;
  const int* l_idx = edges + NE;

  float* out = (float*)d_out;

  // workspace layout
  float* PA = (float*)d_ws;
  float* PP = PA + (size_t)NP * 128;
  float* LA = PP + (size_t)NP * 128;
  float* LP = LA + (size_t)NL * 128;
  int* counts  = (int*)(LP + (size_t)NL * 128);
  int* offsets = counts + NL;
  int* cursor  = offsets + NL;
  int* sorted_p = cursor + NL;

  hipMemsetAsync(counts, 0, (size_t)3 * NL * sizeof(int), stream);

  k_copy4<<<2048, 256, 0, stream>>>((const float4*)h_prot, (float4*)out, NP * 128 / 4);

  k_tables<<<(NP + 7) / 8, 256, 0, stream>>>(h_prot, NP, att_w1, proj_w1,
                                             nullptr, nullptr, PA, PP);
  k_tables<<<(NL + 7) / 8, 256, 0, stream>>>(h_lig, NL, att_w1 + 128 * 128,
                                             proj_w1 + 128 * 128, att_b1, proj_b1, LA, LP);

  k_hist<<<4096, 256, 0, stream>>>(l_idx, NE, counts);
  k_scan<<<1, 1024, 0, stream>>>(counts, offsets, NL);
  k_scatter<<<4096, 256, 0, stream>>>(p_idx, l_idx, NE, offsets, cursor, sorted_p);

  k_edge<<<NL, 256, 0, stream>>>(PA, PP, LA, LP, prot_pos, lig_pos, offsets, counts,
                                 sorted_p, att_w1, att_w2, att_b2, proj_w1, proj_w2,
                                 proj_b2, h_lig, ln_g, ln_b, out, NP);
}

// Round 2
// 863.097 us; speedup vs baseline: 1.3374x; 1.3374x over previous
//
#include <hip/hip_runtime.h>
#include <cstdint>

// ---------------------------------------------------------------------------
// CrossGraphMessagePassing, restructured:
//   PAPP[p][256] = interleaved {h_prot @ att_w1[0:128], h_prot @ proj_w1[0:128]}
//   LA[l] = h_lig @ att_w1[128:256] + b1a ; LP[l] = h_lig @ proj_w1[128:256] + b1p
//   per edge: pre = PAPP[p]+L*+geo@Wg ; silu ; logit=hidden@w2+b2
//             w=exp(logit) (|logit| small -> no segment max), g=exp(-d^2/32)
//             per-ligand accumulate: num += w*g*silu(preP), den += w, gws += w*g
//   per lig:  agg = (num/(den+1e-9)) @ proj_w2 + (gws/(den+1e-9))*proj_b2
//             out = LN(h_lig + agg)
// Edges counting-sorted by ligand; one block == one ligand (no float atomics).
// k_edge is split per wave into Phase A (lane == edge: scalar geo, 18 native
// exps per 64 edges, staged to LDS) and Phase B (wave-wide over 128 dims).
// ---------------------------------------------------------------------------

__device__ __forceinline__ float fast_rcp(float x) { return __builtin_amdgcn_rcpf(x); }
__device__ __forceinline__ float siluf(float x) {
  // x * sigmoid(x) = x / (1 + e^-x); native exp + native rcp (~1 ulp each)
  return x * fast_rcp(1.0f + __expf(-x));
}

__global__ void k_copy4(const float4* __restrict__ s, float4* __restrict__ d, int n) {
  int i = blockIdx.x * blockDim.x + threadIdx.x;
  int stride = gridDim.x * blockDim.x;
  for (; i < n; i += stride) d[i] = s[i];
}

// Tables: 8 rows/block, 256 threads (t<128 -> att col d, t>=128 -> proj col d).
// interleaved==1: write into one [row][256] table as {A0,A1,P0,P1} per dim-pair.
__global__ __launch_bounds__(256) void k_tables(
    const float* __restrict__ h, int nrows,
    const float* __restrict__ Wa, const float* __restrict__ Wp,   // 128x128 (k,d)
    const float* __restrict__ ba, const float* __restrict__ bp,   // nullable
    float* __restrict__ TA, float* __restrict__ TP, int interleaved) {
  __shared__ float hT[128 * 8];  // [k][r]
  int t = threadIdx.x;
  int row0 = blockIdx.x * 8;
  for (int i = t; i < 1024; i += 256) {
    int r = i >> 7, k = i & 127;
    int gr = row0 + r;
    hT[k * 8 + r] = (gr < nrows) ? h[gr * 128 + k] : 0.0f;
  }
  __syncthreads();
  const float* W = (t < 128) ? Wa : Wp;
  const float* bias = (t < 128) ? ba : bp;
  int d = t & 127;
  float acc[8] = {0, 0, 0, 0, 0, 0, 0, 0};
  for (int k = 0; k < 128; ++k) {
    float w = W[k * 128 + d];
    const float4* h4 = reinterpret_cast<const float4*>(&hT[k * 8]);
    float4 a = h4[0], b = h4[1];
    acc[0] += a.x * w; acc[1] += a.y * w; acc[2] += a.z * w; acc[3] += a.w * w;
    acc[4] += b.x * w; acc[5] += b.y * w; acc[6] += b.z * w; acc[7] += b.w * w;
  }
  float bv = bias ? bias[d] : 0.0f;
  if (interleaved) {
    // position within row of 256: 4*(d>>1) + (d&1) + (proj ? 2 : 0)
    int pos = ((d >> 1) << 2) + (d & 1) + ((t < 128) ? 0 : 2);
    #pragma unroll
    for (int r = 0; r < 8; ++r) {
      int gr = row0 + r;
      if (gr < nrows) TA[(size_t)gr * 256 + pos] = acc[r] + bv;
    }
  } else {
    float* T = (t < 128) ? TA : TP;
    #pragma unroll
    for (int r = 0; r < 8; ++r) {
      int gr = row0 + r;
      if (gr < nrows) T[(size_t)gr * 128 + d] = acc[r] + bv;
    }
  }
}

__global__ void k_hist(const int* __restrict__ l_idx, int ne, int* __restrict__ counts) {
  int i = blockIdx.x * blockDim.x + threadIdx.x;
  int stride = gridDim.x * blockDim.x;
  for (; i < ne; i += stride) atomicAdd(&counts[l_idx[i]], 1);
}

__global__ __launch_bounds__(1024) void k_scan(const int* __restrict__ counts,
                                               int* __restrict__ offsets, int n) {
  __shared__ int tsum[1024];
  int t = threadIdx.x;
  int per = (n + 1023) >> 10;
  int base = t * per;
  int s = 0;
  for (int i = 0; i < per; ++i) {
    int idx = base + i;
    if (idx < n) s += counts[idx];
  }
  tsum[t] = s;
  __syncthreads();
  for (int off = 1; off < 1024; off <<= 1) {
    int v = (t >= off) ? tsum[t - off] : 0;
    __syncthreads();
    tsum[t] += v;
    __syncthreads();
  }
  int run = (t == 0) ? 0 : tsum[t - 1];
  for (int i = 0; i < per; ++i) {
    int idx = base + i;
    if (idx < n) {
      offsets[idx] = run;
      run += counts[idx];
    }
  }
}

__global__ void k_scatter(const int* __restrict__ p_idx, const int* __restrict__ l_idx, int ne,
                          const int* __restrict__ offsets, int* __restrict__ cursor,
                          int* __restrict__ sorted_p) {
  int i = blockIdx.x * blockDim.x + threadIdx.x;
  int stride = gridDim.x * blockDim.x;
  for (; i < ne; i += stride) {
    int l = l_idx[i];
    int pos = offsets[l] + atomicAdd(&cursor[l], 1);
    sorted_p[pos] = p_idx[i];
  }
}

// One block (256 threads = 4 waves) per ligand. Lane owns dims 2*lane, 2*lane+1.
// Wave w handles 64-edge chunks [w*64, w*64+64) stepping by 256.
// Phase A: lane == edge (scalar geo, native exps). Phase B: wave-wide per edge.
__global__ __launch_bounds__(256) void k_edge(
    const float* __restrict__ PAPP,
    const float* __restrict__ LA, const float* __restrict__ LP,
    const float* __restrict__ prot_pos, const float* __restrict__ lig_pos,
    const int* __restrict__ offsets, const int* __restrict__ counts,
    const int* __restrict__ sorted_p,
    const float* __restrict__ att_w1, const float* __restrict__ att_w2,
    const float* __restrict__ att_b2,
    const float* __restrict__ proj_w1, const float* __restrict__ proj_w2,
    const float* __restrict__ proj_b2,
    const float* __restrict__ h_lig, const float* __restrict__ ln_g,
    const float* __restrict__ ln_b,
    float* __restrict__ out, int np_total) {
  int l = blockIdx.x;
  int t = threadIdx.x;
  int wave = t >> 6, lane = t & 63;
  int dd = 2 * lane;  // this lane's dim pair: dd, dd+1

  // geo weights (rows 256..275) in registers, per-lane dim pair
  float Ga0[20], Ga1[20], Gp0[20], Gp1[20];
  #pragma unroll
  for (int k = 0; k < 20; ++k) {
    float2 a = *reinterpret_cast<const float2*>(&att_w1[(256 + k) * 128 + dd]);
    float2 p = *reinterpret_cast<const float2*>(&proj_w1[(256 + k) * 128 + dd]);
    Ga0[k] = a.x; Ga1[k] = a.y; Gp0[k] = p.x; Gp1[k] = p.y;
  }
  float2 lav = *reinterpret_cast<const float2*>(&LA[(size_t)l * 128 + dd]);
  float2 lpv = *reinterpret_cast<const float2*>(&LP[(size_t)l * 128 + dd]);
  float2 wav = *reinterpret_cast<const float2*>(&att_w2[dd]);
  float la0 = lav.x, la1 = lav.y, lp0 = lpv.x, lp1 = lpv.y;
  float wa0 = wav.x, wa1 = wav.y;
  float lx = lig_pos[l * 3 + 0], ly = lig_pos[l * 3 + 1], lz = lig_pos[l * 3 + 2];
  float b2 = att_b2[0];

  int start = offsets[l];
  int cnt = counts[l];
  float acc0 = 0.0f, acc1 = 0.0f, den = 0.0f, gws = 0.0f;

  __shared__ float geoS[4][64][24];  // [wave][edge][field]; 96B/edge (16B aligned)
  __shared__ int pS[4][64];

  for (int cbase = wave * 64; cbase < cnt; cbase += 256) {
    int cc = min(64, cnt - cbase);
    // ---- Phase A: one edge per lane ----
    if (lane < cc) {
      int p = sorted_p[start + cbase + lane];
      float px = prot_pos[p * 3 + 0], py = prot_pos[p * 3 + 1], pz = prot_pos[p * 3 + 2];
      float dx = lx - px, dy = ly - py, dz = lz - pz;
      float d2r = dx * dx + dy * dy + dz * dz;
      float dist = sqrtf(d2r);
      float inv = fast_rcp(dist + 1e-8f);
      float4 q0 = make_float4(dist, dx * inv, dy * inv, dz * inv);
      float4 q1, q2, q3, q4;
      float rb[16];
      #pragma unroll
      for (int j = 0; j < 16; ++j) {
        float c = (8.0f / 15.0f) * (float)j;  // linspace(0, 8, 16)
        float ddv = dist - c;
        rb[j] = __expf(-2.0f * ddv * ddv);    // gamma = 2
      }
      q1 = make_float4(rb[0], rb[1], rb[2], rb[3]);
      q2 = make_float4(rb[4], rb[5], rb[6], rb[7]);
      q3 = make_float4(rb[8], rb[9], rb[10], rb[11]);
      q4 = make_float4(rb[12], rb[13], rb[14], rb[15]);
      float g = __expf(-d2r * (1.0f / 32.0f));
      float4* dst = reinterpret_cast<float4*>(&geoS[wave][lane][0]);
      dst[0] = q0; dst[1] = q1; dst[2] = q2; dst[3] = q3; dst[4] = q4;
      geoS[wave][lane][20] = g;
      pS[wave][lane] = p;
    }
    // ---- Phase B: wave-wide over dims, one edge at a time ----
    for (int e = 0; e < cc; ++e) {
      int p = pS[wave][e];
      const float4* gv = reinterpret_cast<const float4*>(&geoS[wave][e][0]);
      float4 q0 = gv[0], q1 = gv[1], q2 = gv[2], q3 = gv[3], q4 = gv[4];
      float g = geoS[wave][e][20];
      float gq[20] = {q0.x, q0.y, q0.z, q0.w, q1.x, q1.y, q1.z, q1.w,
                      q2.x, q2.y, q2.z, q2.w, q3.x, q3.y, q3.z, q3.w,
                      q4.x, q4.y, q4.z, q4.w};
      float4 tv = *reinterpret_cast<const float4*>(&PAPP[(size_t)p * 256 + 4 * lane]);
      float a0 = tv.x + la0, a1 = tv.y + la1;
      float p0 = tv.z + lp0, p1 = tv.w + lp1;
      #pragma unroll
      for (int k = 0; k < 20; ++k) {
        a0 += gq[k] * Ga0[k]; a1 += gq[k] * Ga1[k];
        p0 += gq[k] * Gp0[k]; p1 += gq[k] * Gp1[k];
      }
      float h0 = siluf(a0), h1 = siluf(a1);
      float part = h0 * wa0 + h1 * wa1;
      #pragma unroll
      for (int off = 32; off; off >>= 1) part += __shfl_xor(part, off);
      float w = __expf(part + b2);
      float wg = w * g;
      float s0 = siluf(p0), s1 = siluf(p1);
      acc0 += wg * s0; acc1 += wg * s1;
      den += w; gws += wg;
    }
  }

  __shared__ float num[4][128];
  __shared__ float dsum[4], gsum[4];
  __shared__ float accv[128];
  __shared__ float xrow[128];
  __shared__ float part2[256];
  __shared__ float ssum[2], qsum[2];

  *reinterpret_cast<float2*>(&num[wave][dd]) = make_float2(acc0, acc1);
  if (lane == 0) { dsum[wave] = den; gsum[wave] = gws; }
  __syncthreads();

  if (t < 128) {
    float dtot = dsum[0] + dsum[1] + dsum[2] + dsum[3];
    float invd = 1.0f / (dtot + 1e-9f);
    accv[t] = (num[0][t] + num[1][t] + num[2][t] + num[3][t]) * invd;
  }
  __syncthreads();

  // acc @ proj_w2: split k over the two thread-halves
  int d = t & 127;
  int k0 = (t < 128) ? 0 : 64;
  float sum = 0.0f;
  #pragma unroll 8
  for (int k = k0; k < k0 + 64; ++k) sum += accv[k] * proj_w2[k * 128 + d];
  part2[t] = sum;
  __syncthreads();

  if (t < 128) {
    float dtot = dsum[0] + dsum[1] + dsum[2] + dsum[3];
    float gtot = gsum[0] + gsum[1] + gsum[2] + gsum[3];
    float gval = gtot / (dtot + 1e-9f);
    float x = part2[t] + part2[t + 128] + gval * proj_b2[d] + h_lig[(size_t)l * 128 + d];
    xrow[d] = x;
    float s = x, q = x * x;
    #pragma unroll
    for (int off = 32; off; off >>= 1) {
      s += __shfl_xor(s, off);
      q += __shfl_xor(q, off);
    }
    if (lane == 0) { ssum[wave] = s; qsum[wave] = q; }
  }
  __syncthreads();
  if (t < 128) {
    float x = xrow[d];
    float mu = (ssum[0] + ssum[1]) * (1.0f / 128.0f);
    float var = (qsum[0] + qsum[1]) * (1.0f / 128.0f) - mu * mu;
    float y = (x - mu) * rsqrtf(var + 1e-5f) * ln_g[d] + ln_b[d];
    out[(size_t)(np_total + l) * 128 + d] = y;
  }
}

extern "C" void kernel_launch(void* const* d_in, const int* in_sizes, int n_in,
                              void* d_out, int out_size, void* d_ws, size_t ws_size,
                              hipStream_t stream) {
  const float* h_prot   = (const float*)d_in[0];
  const float* h_lig    = (const float*)d_in[1];
  const float* prot_pos = (const float*)d_in[2];
  const float* lig_pos  = (const float*)d_in[3];
  const int*   edges    = (const int*)d_in[4];
  const float* att_w1   = (const float*)d_in[5];
  const float* att_b1   = (const float*)d_in[6];
  const float* att_w2   = (const float*)d_in[7];
  const float* att_b2   = (const float*)d_in[8];
  const float* proj_w1  = (const float*)d_in[9];
  const float* proj_b1  = (const float*)d_in[10];
  const float* proj_w2  = (const float*)d_in[11];
  const float* proj_b2  = (const float*)d_in[12];
  const float* ln_g     = (const float*)d_in[13];
  const float* ln_b     = (const float*)d_in[14];

  int NP = in_sizes[0] / 128;
  int NL = in_sizes[1] / 128;
  int NE = in_sizes[4] / 2;
  const int* p_idx = edges;
  const int* l_idx = edges + NE;

  float* out = (float*)d_out;

  // workspace layout
  float* PAPP = (float*)d_ws;                      // NP x 256, interleaved A/P
  float* LA = PAPP + (size_t)NP * 256;
  float* LP = LA + (size_t)NL * 128;
  int* counts  = (int*)(LP + (size_t)NL * 128);
  int* offsets = counts + NL;
  int* cursor  = offsets + NL;
  int* sorted_p = cursor + NL;

  hipMemsetAsync(counts, 0, (size_t)3 * NL * sizeof(int), stream);

  k_copy4<<<2048, 256, 0, stream>>>((const float4*)h_prot, (float4*)out, NP * 128 / 4);

  k_tables<<<(NP + 7) / 8, 256, 0, stream>>>(h_prot, NP, att_w1, proj_w1,
                                             nullptr, nullptr, PAPP, nullptr, 1);
  k_tables<<<(NL + 7) / 8, 256, 0, stream>>>(h_lig, NL, att_w1 + 128 * 128,
                                             proj_w1 + 128 * 128, att_b1, proj_b1,
                                             LA, LP, 0);

  k_hist<<<4096, 256, 0, stream>>>(l_idx, NE, counts);
  k_scan<<<1, 1024, 0, stream>>>(counts, offsets, NL);
  k_scatter<<<4096, 256, 0, stream>>>(p_idx, l_idx, NE, offsets, cursor, sorted_p);

  k_edge<<<NL, 256, 0, stream>>>(PAPP, LA, LP, prot_pos, lig_pos, offsets, counts,
                                 sorted_p, att_w1, att_w2, att_b2, proj_w1, proj_w2,
                                 proj_b2, h_lig, ln_g, ln_b, out, NP);
}

// Round 3
// 680.699 us; speedup vs baseline: 1.6958x; 1.2680x over previous
//
#include <hip/hip_runtime.h>
#include <cstdint>

// ---------------------------------------------------------------------------
// CrossGraphMessagePassing:
//   PAPP[p][256] = interleaved {h_prot @ att_w1[0:128], h_prot @ proj_w1[0:128]}
//   LA[l] = h_lig @ att_w1[128:256] + b1a ; LP[l] = h_lig @ proj_w1[128:256] + b1p
//   Gq[20][256]  = geo-weight rows (att/proj interleaved per lane dim-pair)
//   per edge: pre = PAPP[p]+L+geo@Wg ; logit = silu(pre_a)@w2+b2
//             w=exp(logit) (|logit| small -> segment-max not needed), g=exp(-d^2/32)
//             per-ligand: num += w*g*silu(pre_p), den += w, gws += w*g
//   per lig:  agg = (num/den)@proj_w2 + (gws/den)*proj_b2 ; out = LN(h_lig+agg)
// Edges counting-sorted by ligand. k_edge: ONE WAVE PER LIGAND (no barriers,
// no idle waves), Phase A (lane==edge: scalar geo, native exps -> LDS),
// Phase B (wave-wide over dims, 2 edges in flight).
// ---------------------------------------------------------------------------

__device__ __forceinline__ float fast_rcp(float x) { return __builtin_amdgcn_rcpf(x); }
__device__ __forceinline__ float siluf(float x) { return x * fast_rcp(1.0f + __expf(-x)); }

__global__ void k_copy4(const float4* __restrict__ s, float4* __restrict__ d, int n) {
  int i = blockIdx.x * blockDim.x + threadIdx.x;
  int stride = gridDim.x * blockDim.x;
  for (; i < n; i += stride) d[i] = s[i];
}

// Tables: 8 rows/block, 256 threads (t<128 -> att col d, t>=128 -> proj col d).
// interleaved==1: write into one [row][256] table as {A0,A1,P0,P1} per dim-pair.
__global__ __launch_bounds__(256) void k_tables(
    const float* __restrict__ h, int nrows,
    const float* __restrict__ Wa, const float* __restrict__ Wp,   // 128x128 (k,d)
    const float* __restrict__ ba, const float* __restrict__ bp,   // nullable
    float* __restrict__ TA, float* __restrict__ TP, int interleaved) {
  __shared__ float hT[128 * 8];  // [k][r]
  int t = threadIdx.x;
  int row0 = blockIdx.x * 8;
  for (int i = t; i < 1024; i += 256) {
    int r = i >> 7, k = i & 127;
    int gr = row0 + r;
    hT[k * 8 + r] = (gr < nrows) ? h[gr * 128 + k] : 0.0f;
  }
  __syncthreads();
  const float* W = (t < 128) ? Wa : Wp;
  const float* bias = (t < 128) ? ba : bp;
  int d = t & 127;
  float acc[8] = {0, 0, 0, 0, 0, 0, 0, 0};
  for (int k = 0; k < 128; ++k) {
    float w = W[k * 128 + d];
    const float4* h4 = reinterpret_cast<const float4*>(&hT[k * 8]);
    float4 a = h4[0], b = h4[1];
    acc[0] += a.x * w; acc[1] += a.y * w; acc[2] += a.z * w; acc[3] += a.w * w;
    acc[4] += b.x * w; acc[5] += b.y * w; acc[6] += b.z * w; acc[7] += b.w * w;
  }
  float bv = bias ? bias[d] : 0.0f;
  if (interleaved) {
    int pos = ((d >> 1) << 2) + (d & 1) + ((t < 128) ? 0 : 2);
    #pragma unroll
    for (int r = 0; r < 8; ++r) {
      int gr = row0 + r;
      if (gr < nrows) TA[(size_t)gr * 256 + pos] = acc[r] + bv;
    }
  } else {
    float* T = (t < 128) ? TA : TP;
    #pragma unroll
    for (int r = 0; r < 8; ++r) {
      int gr = row0 + r;
      if (gr < nrows) T[(size_t)gr * 128 + d] = acc[r] + bv;
    }
  }
}

// Gq[k][4*lane + c]: c=0 -> att_w1[(256+k)][2*lane], c=1 -> att_w1[..][2*lane+1],
//                    c=2 -> proj_w1[(256+k)][2*lane], c=3 -> proj_w1[..][2*lane+1]
__global__ void k_geow(const float* __restrict__ att_w1, const float* __restrict__ proj_w1,
                       float* __restrict__ Gq) {
  int i = blockIdx.x * blockDim.x + threadIdx.x;
  if (i >= 20 * 256) return;
  int k = i >> 8, j = i & 255;
  int lane = j >> 2, c = j & 3;
  int d = 2 * lane + (c & 1);
  const float* src = (c < 2) ? att_w1 : proj_w1;
  Gq[i] = src[(256 + k) * 128 + d];
}

__global__ void k_hist(const int* __restrict__ l_idx, int ne, int* __restrict__ counts) {
  int i = blockIdx.x * blockDim.x + threadIdx.x;
  int stride = gridDim.x * blockDim.x;
  for (; i < ne; i += stride) atomicAdd(&counts[l_idx[i]], 1);
}

__global__ __launch_bounds__(1024) void k_scan(const int* __restrict__ counts,
                                               int* __restrict__ offsets,
                                               int* __restrict__ cursor, int n) {
  __shared__ int tsum[1024];
  int t = threadIdx.x;
  int per = (n + 1023) >> 10;
  int base = t * per;
  int s = 0;
  for (int i = 0; i < per; ++i) {
    int idx = base + i;
    if (idx < n) s += counts[idx];
  }
  tsum[t] = s;
  __syncthreads();
  for (int off = 1; off < 1024; off <<= 1) {
    int v = (t >= off) ? tsum[t - off] : 0;
    __syncthreads();
    tsum[t] += v;
    __syncthreads();
  }
  int run = (t == 0) ? 0 : tsum[t - 1];
  for (int i = 0; i < per; ++i) {
    int idx = base + i;
    if (idx < n) {
      offsets[idx] = run;
      cursor[idx] = run;
      run += counts[idx];
    }
  }
}

__global__ void k_scatter(const int* __restrict__ p_idx, const int* __restrict__ l_idx, int ne,
                          int* __restrict__ cursor, int* __restrict__ sorted_p) {
  int i = blockIdx.x * blockDim.x + threadIdx.x;
  int stride = gridDim.x * blockDim.x;
  for (; i < ne; i += stride) {
    int l = l_idx[i];
    int pos = atomicAdd(&cursor[l], 1);
    sorted_p[pos] = p_idx[i];
  }
}

// ONE WAVE PER LIGAND. 256 threads = 4 waves = 4 ligands/block. No barriers.
// Lane owns dims dd=2*lane, dd+1. Phase A: lane==edge (geo -> LDS).
// Phase B: wave-wide per edge, 2 edges in flight.
__global__ __launch_bounds__(256) void k_edge(
    const float* __restrict__ PAPP, const float* __restrict__ Gq,
    const float* __restrict__ LA, const float* __restrict__ LP,
    const float* __restrict__ prot_pos, const float* __restrict__ lig_pos,
    const int* __restrict__ offsets, const int* __restrict__ counts,
    const int* __restrict__ sorted_p,
    const float* __restrict__ att_w2, const float* __restrict__ att_b2,
    const float* __restrict__ proj_w2, const float* __restrict__ proj_b2,
    const float* __restrict__ h_lig, const float* __restrict__ ln_g,
    const float* __restrict__ ln_b,
    float* __restrict__ out, int np_total, int nl_total) {
  __shared__ alignas(16) float geoS[4][64][24];  // [wave][edge][field]
  __shared__ alignas(16) int pS[4][64];
  __shared__ alignas(16) float accS[4][128];

  int t = threadIdx.x;
  int wave = t >> 6, lane = t & 63;
  int l = blockIdx.x * 4 + wave;
  if (l >= nl_total) return;  // whole-wave exit; kernel has no barriers
  int dd = 2 * lane;

  // per-lane geo weights: 20 x float4 {Ga(dd), Ga(dd+1), Gp(dd), Gp(dd+1)}
  const float4* Gq4 = reinterpret_cast<const float4*>(Gq);
  float4 G[20];
  #pragma unroll
  for (int k = 0; k < 20; ++k) G[k] = Gq4[k * 64 + lane];

  float2 lav = *reinterpret_cast<const float2*>(&LA[(size_t)l * 128 + dd]);
  float2 lpv = *reinterpret_cast<const float2*>(&LP[(size_t)l * 128 + dd]);
  float2 wav = *reinterpret_cast<const float2*>(&att_w2[dd]);
  float la0 = lav.x, la1 = lav.y, lp0 = lpv.x, lp1 = lpv.y;
  float wa0 = wav.x, wa1 = wav.y;
  float lx = lig_pos[l * 3 + 0], ly = lig_pos[l * 3 + 1], lz = lig_pos[l * 3 + 2];
  float b2 = att_b2[0];

  int start = offsets[l];
  int cnt = counts[l];
  float acc0 = 0.0f, acc1 = 0.0f, den = 0.0f, gws = 0.0f;

  const float4* PAPP4 = reinterpret_cast<const float4*>(PAPP);

  for (int cbase = 0; cbase < cnt; cbase += 64) {
    int cc = min(64, cnt - cbase);
    // ---- Phase A: one edge per lane ----
    if (lane < cc) {
      int p = sorted_p[start + cbase + lane];
      float px = prot_pos[p * 3 + 0], py = prot_pos[p * 3 + 1], pz = prot_pos[p * 3 + 2];
      float dx = lx - px, dy = ly - py, dz = lz - pz;
      float d2r = dx * dx + dy * dy + dz * dz;
      float dist = sqrtf(d2r);
      float inv = fast_rcp(dist + 1e-8f);
      float rb[16];
      #pragma unroll
      for (int j = 0; j < 16; ++j) {
        float c = (8.0f / 15.0f) * (float)j;  // linspace(0, 8, 16)
        float dv = dist - c;
        rb[j] = __expf(-2.0f * dv * dv);      // gamma = 2
      }
      float4* dst = reinterpret_cast<float4*>(&geoS[wave][lane][0]);
      dst[0] = make_float4(dist, dx * inv, dy * inv, dz * inv);
      dst[1] = make_float4(rb[0], rb[1], rb[2], rb[3]);
      dst[2] = make_float4(rb[4], rb[5], rb[6], rb[7]);
      dst[3] = make_float4(rb[8], rb[9], rb[10], rb[11]);
      dst[4] = make_float4(rb[12], rb[13], rb[14], rb[15]);
      geoS[wave][lane][20] = __expf(-d2r * (1.0f / 32.0f));
      pS[wave][lane] = p;
    }
    // ---- Phase B: wave-wide, 2 edges in flight ----
    int e = 0;
    while (e < cc) {
      int n2 = (cc - e >= 2) ? 2 : 1;
      int eB = e + n2 - 1;
      int pA = pS[wave][e];
      int pB = pS[wave][eB];
      float4 tvA = PAPP4[(size_t)pA * 64 + lane];
      float4 tvB = PAPP4[(size_t)pB * 64 + lane];
      float aA0 = tvA.x + la0, aA1 = tvA.y + la1, pA0 = tvA.z + lp0, pA1 = tvA.w + lp1;
      float aB0 = tvB.x + la0, aB1 = tvB.y + la1, pB0 = tvB.z + lp0, pB1 = tvB.w + lp1;
      const float4* gA4 = reinterpret_cast<const float4*>(&geoS[wave][e][0]);
      const float4* gB4 = reinterpret_cast<const float4*>(&geoS[wave][eB][0]);
      #pragma unroll
      for (int k4 = 0; k4 < 5; ++k4) {
        float4 qA = gA4[k4];
        float4 qB = gB4[k4];
        int k = 4 * k4;
        aA0 += qA.x * G[k].x;     aA1 += qA.x * G[k].y;
        pA0 += qA.x * G[k].z;     pA1 += qA.x * G[k].w;
        aB0 += qB.x * G[k].x;     aB1 += qB.x * G[k].y;
        pB0 += qB.x * G[k].z;     pB1 += qB.x * G[k].w;
        aA0 += qA.y * G[k + 1].x; aA1 += qA.y * G[k + 1].y;
        pA0 += qA.y * G[k + 1].z; pA1 += qA.y * G[k + 1].w;
        aB0 += qB.y * G[k + 1].x; aB1 += qB.y * G[k + 1].y;
        pB0 += qB.y * G[k + 1].z; pB1 += qB.y * G[k + 1].w;
        aA0 += qA.z * G[k + 2].x; aA1 += qA.z * G[k + 2].y;
        pA0 += qA.z * G[k + 2].z; pA1 += qA.z * G[k + 2].w;
        aB0 += qB.z * G[k + 2].x; aB1 += qB.z * G[k + 2].y;
        pB0 += qB.z * G[k + 2].z; pB1 += qB.z * G[k + 2].w;
        aA0 += qA.w * G[k + 3].x; aA1 += qA.w * G[k + 3].y;
        pA0 += qA.w * G[k + 3].z; pA1 += qA.w * G[k + 3].w;
        aB0 += qB.w * G[k + 3].x; aB1 += qB.w * G[k + 3].y;
        pB0 += qB.w * G[k + 3].z; pB1 += qB.w * G[k + 3].w;
      }
      float gA = geoS[wave][e][20];
      float gB = geoS[wave][eB][20];
      float partA = siluf(aA0) * wa0 + siluf(aA1) * wa1;
      float partB = siluf(aB0) * wa0 + siluf(aB1) * wa1;
      #pragma unroll
      for (int off = 32; off; off >>= 1) {
        partA += __shfl_xor(partA, off);
        partB += __shfl_xor(partB, off);
      }
      float wA = __expf(partA + b2);
      float wB = __expf(partB + b2);
      float sA0 = siluf(pA0), sA1 = siluf(pA1);
      float sB0 = siluf(pB0), sB1 = siluf(pB1);
      float wgA = wA * gA, wgB = wB * gB;
      if (n2 == 2) {
        acc0 += wgA * sA0 + wgB * sB0;
        acc1 += wgA * sA1 + wgB * sB1;
        den += wA + wB;
        gws += wgA + wgB;
      } else {
        acc0 += wgA * sA0;
        acc1 += wgA * sA1;
        den += wA;
        gws += wgA;
      }
      e += n2;
    }
  }

  // ---- per-wave epilogue (no barriers) ----
  float invd = 1.0f / (den + 1e-9f);
  accS[wave][dd] = acc0 * invd;
  accS[wave][dd + 1] = acc1 * invd;
  // same-wave LDS RAW: compiler inserts lgkmcnt wait
  const float2* W2_2 = reinterpret_cast<const float2*>(proj_w2);
  float agg0 = 0.0f, agg1 = 0.0f;
  #pragma unroll 4
  for (int k = 0; k < 128; k += 4) {
    float4 av = *reinterpret_cast<const float4*>(&accS[wave][k]);
    float2 w0 = W2_2[(size_t)(k + 0) * 64 + lane];
    float2 w1 = W2_2[(size_t)(k + 1) * 64 + lane];
    float2 w2 = W2_2[(size_t)(k + 2) * 64 + lane];
    float2 w3 = W2_2[(size_t)(k + 3) * 64 + lane];
    agg0 += av.x * w0.x + av.y * w1.x + av.z * w2.x + av.w * w3.x;
    agg1 += av.x * w0.y + av.y * w1.y + av.z * w2.y + av.w * w3.y;
  }
  float gval = gws * invd;
  float2 pb2 = *reinterpret_cast<const float2*>(&proj_b2[dd]);
  float2 hl = *reinterpret_cast<const float2*>(&h_lig[(size_t)l * 128 + dd]);
  float x0 = agg0 + gval * pb2.x + hl.x;
  float x1 = agg1 + gval * pb2.y + hl.y;
  float s = x0 + x1, q = x0 * x0 + x1 * x1;
  #pragma unroll
  for (int off = 32; off; off >>= 1) {
    s += __shfl_xor(s, off);
    q += __shfl_xor(q, off);
  }
  float mu = s * (1.0f / 128.0f);
  float var = q * (1.0f / 128.0f) - mu * mu;
  float rstd = rsqrtf(var + 1e-5f);
  float2 gm = *reinterpret_cast<const float2*>(&ln_g[dd]);
  float2 bt = *reinterpret_cast<const float2*>(&ln_b[dd]);
  float2 y = make_float2((x0 - mu) * rstd * gm.x + bt.x,
                         (x1 - mu) * rstd * gm.y + bt.y);
  *reinterpret_cast<float2*>(&out[(size_t)(np_total + l) * 128 + dd]) = y;
}

extern "C" void kernel_launch(void* const* d_in, const int* in_sizes, int n_in,
                              void* d_out, int out_size, void* d_ws, size_t ws_size,
                              hipStream_t stream) {
  const float* h_prot   = (const float*)d_in[0];
  const float* h_lig    = (const float*)d_in[1];
  const float* prot_pos = (const float*)d_in[2];
  const float* lig_pos  = (const float*)d_in[3];
  const int*   edges    = (const int*)d_in[4];
  const float* att_w1   = (const float*)d_in[5];
  const float* att_b1   = (const float*)d_in[6];
  const float* att_w2   = (const float*)d_in[7];
  const float* att_b2   = (const float*)d_in[8];
  const float* proj_w1  = (const float*)d_in[9];
  const float* proj_b1  = (const float*)d_in[10];
  const float* proj_w2  = (const float*)d_in[11];
  const float* proj_b2  = (const float*)d_in[12];
  const float* ln_g     = (const float*)d_in[13];
  const float* ln_b     = (const float*)d_in[14];

  int NP = in_sizes[0] / 128;
  int NL = in_sizes[1] / 128;
  int NE = in_sizes[4] / 2;
  const int* p_idx = edges;
  const int* l_idx = edges + NE;

  float* out = (float*)d_out;

  // workspace layout
  float* PAPP = (float*)d_ws;                      // NP x 256, interleaved A/P
  float* LA = PAPP + (size_t)NP * 256;
  float* LP = LA + (size_t)NL * 128;
  float* Gq = LP + (size_t)NL * 128;               // 20 x 256
  int* counts  = (int*)(Gq + 20 * 256);
  int* offsets = counts + NL;
  int* cursor  = offsets + NL;
  int* sorted_p = cursor + NL;

  hipMemsetAsync(counts, 0, (size_t)NL * sizeof(int), stream);

  k_copy4<<<2048, 256, 0, stream>>>((const float4*)h_prot, (float4*)out, NP * 128 / 4);

  k_tables<<<(NP + 7) / 8, 256, 0, stream>>>(h_prot, NP, att_w1, proj_w1,
                                             nullptr, nullptr, PAPP, nullptr, 1);
  k_tables<<<(NL + 7) / 8, 256, 0, stream>>>(h_lig, NL, att_w1 + 128 * 128,
                                             proj_w1 + 128 * 128, att_b1, proj_b1,
                                             LA, LP, 0);
  k_geow<<<20, 256, 0, stream>>>(att_w1, proj_w1, Gq);

  k_hist<<<4096, 256, 0, stream>>>(l_idx, NE, counts);
  k_scan<<<1, 1024, 0, stream>>>(counts, offsets, cursor, NL);
  k_scatter<<<4096, 256, 0, stream>>>(p_idx, l_idx, NE, cursor, sorted_p);

  k_edge<<<(NL + 3) / 4, 256, 0, stream>>>(PAPP, Gq, LA, LP, prot_pos, lig_pos,
                                           offsets, counts, sorted_p,
                                           att_w2, att_b2, proj_w2, proj_b2,
                                           h_lig, ln_g, ln_b, out, NP, NL);
}